// Round 4
// baseline (382.269 us; speedup 1.0000x reference)
//
#include <hip/hip_runtime.h>

static constexpr int NB = 512;     // batch
static constexpr int L  = 512;     // points per cloud
static constexpr int F  = 64;      // input features
static constexpr int H  = 128;     // hidden features
static constexpr float EPS = 1e-5f;

#define XSTR 68     // x LDS row stride (floats); 64 rows
#define WSTR 132    // W LDS row stride (floats); layout [k][h]

// One block per cloud n. 256 threads: tc=tid&15 -> h0=tc*8, tr=tid>>4 -> 4 rows.
// Does GEMM(x W^T + b) -> LayerNorm -> ReLU -> y-store, masked max over L in-block,
// then broadcast-stores g into the second half of every row + the g tail.
__global__ __launch_bounds__(256)
void ClusterLayer_24524263260901_kernel(
    const float* __restrict__ xp, const int* __restrict__ maskp,
    const float* __restrict__ Wp, const float* __restrict__ bp,
    const float* __restrict__ gp, const float* __restrict__ betap,
    float* __restrict__ outp)
{
    __shared__ float wlds[F * WSTR];     // 33792 B, wlds[k][h] = W[h][k]
    __shared__ float xlds[64 * XSTR];    // 17408 B, 64-row x chunk
    __shared__ float gsh[4][H];          // per-wave g partials; gsh[0] holds final g

    const int n   = blockIdx.x;
    const int tid = threadIdx.x;
    const int tc  = tid & 15;
    const int tr  = tid >> 4;
    const int h0  = tc * 8;
    const int r0  = tr * 4;
    const int wv  = tid >> 6;

    // ---- stage W transposed into LDS (once per block) ----
    #pragma unroll
    for (int it = 0; it < 8; ++it) {
        const int i  = it * 256 + tid;   // float4 index, 0..2047
        const int h  = i >> 4;
        const int kg = i & 15;
        const float4 v = *(const float4*)(Wp + h * F + kg * 4);
        wlds[(kg * 4 + 0) * WSTR + h] = v.x;
        wlds[(kg * 4 + 1) * WSTR + h] = v.y;
        wlds[(kg * 4 + 2) * WSTR + h] = v.z;
        wlds[(kg * 4 + 3) * WSTR + h] = v.w;
    }

    // ---- per-h params ----
    float bias[8], gam[8], bet[8];
    #pragma unroll
    for (int hi = 0; hi < 8; ++hi) {
        bias[hi] = bp[h0 + hi];
        gam[hi]  = gp[h0 + hi];
        bet[hi]  = betap[h0 + hi];
    }

    float gmax[8];
    #pragma unroll
    for (int hi = 0; hi < 8; ++hi) gmax[hi] = 0.0f;

    // ---- 8 chunks of 64 rows ----
    for (int chunk = 0; chunk < 8; ++chunk) {
        const int rowbase = n * L + chunk * 64;
        __syncthreads();   // xlds free (also covers W staging on first iter)
        #pragma unroll
        for (int it = 0; it < 4; ++it) {
            const int i  = it * 256 + tid;   // float4 index, 0..1023
            const int r  = i >> 4;
            const int kg = i & 15;
            *(float4*)&xlds[r * XSTR + kg * 4] =
                *(const float4*)(xp + (size_t)(rowbase + r) * F + kg * 4);
        }
        __syncthreads();

        float acc[4][8];
        #pragma unroll
        for (int ri = 0; ri < 4; ++ri)
            #pragma unroll
            for (int hi = 0; hi < 8; ++hi) acc[ri][hi] = 0.0f;

        #pragma unroll
        for (int kb = 0; kb < 16; ++kb) {
            float xk[4][4];
            #pragma unroll
            for (int ri = 0; ri < 4; ++ri) {
                const float4 xv = *(const float4*)&xlds[(r0 + ri) * XSTR + kb * 4];
                xk[ri][0] = xv.x; xk[ri][1] = xv.y; xk[ri][2] = xv.z; xk[ri][3] = xv.w;
            }
            #pragma unroll
            for (int j = 0; j < 4; ++j) {
                const float4 w0 = *(const float4*)&wlds[(kb * 4 + j) * WSTR + h0];
                const float4 w1 = *(const float4*)&wlds[(kb * 4 + j) * WSTR + h0 + 4];
                #pragma unroll
                for (int ri = 0; ri < 4; ++ri) {
                    const float a = xk[ri][j];
                    acc[ri][0] += a * w0.x; acc[ri][1] += a * w0.y;
                    acc[ri][2] += a * w0.z; acc[ri][3] += a * w0.w;
                    acc[ri][4] += a * w1.x; acc[ri][5] += a * w1.y;
                    acc[ri][6] += a * w1.z; acc[ri][7] += a * w1.w;
                }
            }
        }

        // ---- bias, LayerNorm, ReLU, store, masked max ----
        #pragma unroll
        for (int ri = 0; ri < 4; ++ri) {
            const int grow = rowbase + r0 + ri;          // = n*L + l
            float s = 0.0f, q = 0.0f;
            #pragma unroll
            for (int hi = 0; hi < 8; ++hi) {
                const float v = acc[ri][hi] + bias[hi];
                acc[ri][hi] = v;
                s += v; q += v * v;
            }
            #pragma unroll
            for (int o = 1; o < 16; o <<= 1) {           // sum over the 16 tc lanes
                s += __shfl_xor(s, o);
                q += __shfl_xor(q, o);
            }
            const float mu  = s * (1.0f / 128.0f);
            const float var = q * (1.0f / 128.0f) - mu * mu;
            const float rsg = rsqrtf(var + EPS);
            const int   mk  = maskp[grow];

            float4 y0, y1;
            float yv[8];
            #pragma unroll
            for (int hi = 0; hi < 8; ++hi) {
                float y = (acc[ri][hi] - mu) * rsg * gam[hi] + bet[hi];
                y = fmaxf(y, 0.0f);
                yv[hi] = y;
                if (mk != 0) gmax[hi] = fmaxf(gmax[hi], y);
            }
            y0.x = yv[0]; y0.y = yv[1]; y0.z = yv[2]; y0.w = yv[3];
            y1.x = yv[4]; y1.y = yv[5]; y1.z = yv[6]; y1.w = yv[7];
            float* orow = outp + (size_t)grow * (2 * H) + h0;
            *(float4*)(orow)     = y0;
            *(float4*)(orow + 4) = y1;
        }
    }

    // ---- reduce gmax across tr groups ----
    #pragma unroll
    for (int hi = 0; hi < 8; ++hi) {
        gmax[hi] = fmaxf(gmax[hi], __shfl_xor(gmax[hi], 16));
        gmax[hi] = fmaxf(gmax[hi], __shfl_xor(gmax[hi], 32));
    }
    if ((tid & 63) < 16) {
        #pragma unroll
        for (int hi = 0; hi < 8; ++hi)
            gsh[wv][h0 + hi] = gmax[hi];
    }
    __syncthreads();
    if (tid < H) {
        float m = fmaxf(fmaxf(gsh[0][tid], gsh[1][tid]),
                        fmaxf(gsh[2][tid], gsh[3][tid]));
        gsh[0][tid] = m;
        // g tail: out offset NB*L*2H + n*H + tid
        outp[(size_t)NB * L * (2 * H) + (size_t)n * H + tid] = m;
    }
    __syncthreads();

    // ---- broadcast g into the second half of every row ----
    const float4 g0 = *(const float4*)&gsh[0][h0];
    const float4 g1 = *(const float4*)&gsh[0][h0 + 4];
    #pragma unroll
    for (int p = 0; p < 32; ++p) {
        const int l = p * 16 + tr;
        float* orow = outp + ((size_t)n * L + l) * (2 * H) + H + h0;
        *(float4*)(orow)     = g0;
        *(float4*)(orow + 4) = g1;
    }
}

extern "C" void kernel_launch(void* const* d_in, const int* in_sizes, int n_in,
                              void* d_out, int out_size, void* d_ws, size_t ws_size,
                              hipStream_t stream)
{
    (void)in_sizes; (void)n_in; (void)out_size; (void)d_ws; (void)ws_size;
    const float* x     = (const float*)d_in[0];
    const int*   mask  = (const int*)d_in[1];
    const float* W     = (const float*)d_in[2];
    const float* b     = (const float*)d_in[3];
    const float* gamma = (const float*)d_in[4];
    const float* beta  = (const float*)d_in[5];
    float* out = (float*)d_out;

    ClusterLayer_24524263260901_kernel<<<dim3(NB), dim3(256), 0, stream>>>(
        x, mask, W, b, gamma, beta, out);
}